// Round 6
// baseline (442.673 us; speedup 1.0000x reference)
//
#include <hip/hip_runtime.h>
#include <cstdint>

typedef __bf16          bf16x8 __attribute__((ext_vector_type(8)));
typedef float           f32x4  __attribute__((ext_vector_type(4)));
typedef unsigned short  u16x8  __attribute__((ext_vector_type(8)));

#define MFMA16(a,b,c) __builtin_amdgcn_mfma_f32_16x16x32_bf16((a),(b),(c),0,0,0)

__device__ __forceinline__ float rcpf(float x) { return __builtin_amdgcn_rcpf(x); }
__device__ __forceinline__ float ex2(float x)  { return __builtin_amdgcn_exp2f(x); }

// truncation hi/lo split: hi = top16(v), lo = trunc16(v - hi).
__device__ __forceinline__ void split2(float v, unsigned short& hi, unsigned short& lo) {
    unsigned u = __builtin_bit_cast(unsigned, v);
    hi = (unsigned short)(u >> 16);
    float rem = v - __builtin_bit_cast(float, u & 0xffff0000u);
    lo = (unsigned short)(__builtin_bit_cast(unsigned, rem) >> 16);
}
__device__ __forceinline__ __bf16 bfbits(unsigned short b) { return __builtin_bit_cast(__bf16, b); }

// ---------------------------------------------------------------------------
// 3-role pipeline, 6 waves/SIMD. Block = 6 waves = 2 groups x 3 roles:
//   W0: lstm0 step i.   W1: lstm1 step i-1 (h1 wave-private, in-place).
//   W2: input proj step i+1 (only Ph/Pl weights -> low VGPR).
// R5 post-mortem: VALU-issue-bound at 65% util with 4 waves/SIMD; regular
// VALU (not trans) dominates. This round: +TLP (6/SIMD, launch_bounds(384,6),
// VGPR cap ~85 vs measured 52) and -VALU (persistent zero C operand kills
// 36 v_movs/group-step; d16_hi store pattern for hi-plane writes).
// Bias row k=13 vs constant 1.0 at staging pos 13 (col<13-masked writes
// preserve it); weight rows k>=29 are zero so pos13 is harmless as hidden.
// R3 lesson: never let weight arrays exceed the per-wave VGPR cap (spills
// showed as WRITE_SIZE 79 MB). R4 lesson: cell state must be float[4].
// ---------------------------------------------------------------------------

constexpr float KL = 1.4426950408889634f;   // log2(e)

__global__ __launch_bounds__(384, 6)
void lstm_fused(const float* __restrict__ x,
                const float* __restrict__ w_hidden,
                const float* __restrict__ b_hidden,
                const float* __restrict__ k0,
                const float* __restrict__ b0,
                const float* __restrict__ k1,
                const float* __restrict__ b1,
                const float* __restrict__ w_out,
                const float* __restrict__ b_out,
                float* __restrict__ out)
{
    __shared__ __attribute__((aligned(16))) unsigned short xh_s[2][2][2][384];
    __shared__ __attribute__((aligned(16))) unsigned short h0_s[2][2][2][384];
    __shared__ __attribute__((aligned(16))) unsigned short h1_s[2][2][384];

    const int lane = threadIdx.x & 63;
    const int wv   = threadIdx.x >> 6;
    const int grp  = wv / 3;
    const int role = wv % 3;
    const int col  = lane & 15;
    const int q    = lane >> 4;
    const int qh   = q & 1;
    const int s0   = (blockIdx.x * 2 + grp) * 16;

    // ---- init staging: zeros + 1.0 at hi-plane pos 13 of every row ----
    {
        unsigned short* a0 = &xh_s[0][0][0][0];
        unsigned short* a1 = &h0_s[0][0][0][0];
        for (int idx = threadIdx.x; idx < 3072; idx += 384) {
            unsigned short v = ((idx % 24) == 13 && ((idx / 384) & 1) == 0)
                             ? (unsigned short)0x3F80 : (unsigned short)0;
            a0[idx] = v; a1[idx] = v;
        }
        unsigned short* a2 = &h1_s[0][0][0];
        for (int idx = threadIdx.x; idx < 1536; idx += 384) {
            unsigned short v = ((idx % 24) == 13 && ((idx / 384) & 1) == 0)
                             ? (unsigned short)0x3F80 : (unsigned short)0;
            a2[idx] = v;
        }
    }

    // ---- weights. W0/W1: LSTM kernel as B-frags (bias row k=13).
    //      W2 aliases Kh[0]=proj hi, Kh[1]=proj lo (keeps union small). ----
    bf16x8 Kh[4], Kl[4];
    if (role < 2) {
        const float* kp = role ? k1 : k0;
        const float* bb = role ? b1 : b0;
        #pragma unroll
        for (int g = 0; g < 4; ++g) {
            bf16x8 hv{}, lv{};
            #pragma unroll
            for (int j = 0; j < 8; ++j) {
                int k = 8 * q + j;
                float w = 0.f;
                if (col < 13) {
                    if (k < 13)                 w = kp[k * 52 + 13 * g + col];
                    else if (k == 13)           w = bb[13 * g + col] + (g == 2 ? 1.f : 0.f); // +FORGET_BIAS on f
                    else if (k >= 16 && k < 29) w = kp[(13 + k - 16) * 52 + 13 * g + col];
                }
                unsigned short h_, l_;
                split2(w, h_, l_);
                hv[j] = bfbits(h_); lv[j] = bfbits(l_);
            }
            Kh[g] = hv; Kl[g] = lv;
        }
    } else {
        bf16x8 hv{}, lv{};
        #pragma unroll
        for (int j = 0; j < 8; ++j) {
            int k = 8 * q + j;
            float w = 0.f;
            if (col < 13) {
                if (k < 13)       w = w_hidden[k * 13 + col];
                else if (k == 13) w = b_hidden[col];
            }
            unsigned short h_, l_;
            split2(w, h_, l_);
            hv[j] = bfbits(h_); lv[j] = bfbits(l_);
        }
        Kh[0] = hv; Kh[1] = lv;
    }

    const float* xrow = x + (size_t)(s0 + col) * 1300;

    // persistent zero C operand: no per-step accumulator-init movs
    const f32x4 Z4 = {0.f, 0.f, 0.f, 0.f};

    // 7-trans elementwise: 5 exp + 2 rcp per value
    auto elem = [&](float zi, float zj, float zf, float zo, float& c) -> float {
        float a   = ex2(-KL * zi);
        float b   = ex2(-2.f * KL * zj);
        float fe  = ex2(-KL * zf);
        float g   = ex2(-KL * zo);
        float opa = 1.f + a, opb = 1.f + b, opf = 1.f + fe;
        float pab = opa * opb;
        float r1  = rcpf(pab * opf);
        float cn  = fmaf(c, pab, (1.f - b) * opf) * r1;   // c*sig(f) + sig(i)*tanh(j)
        c = cn;
        float d   = ex2(-2.f * KL * cn);
        float r2  = rcpf((1.f + d) * (1.f + g));
        return (1.f - d) * r2;                            // tanh(cn)*sig(o)
    };

    auto cell = [&](const unsigned short* inH, const unsigned short* hidH,
                    unsigned short* outH, float* cst) {
        const unsigned short* pA = (q < 2) ? inH : hidH;
        bf16x8 ah = __builtin_bit_cast(bf16x8, *(const u16x8*)(pA + col * 24 + 8 * qh));
        bf16x8 al = __builtin_bit_cast(bf16x8, *(const u16x8*)(pA + 384 + col * 24 + 8 * qh));
        f32x4 z0 = MFMA16(ah, Kh[0], Z4);
        f32x4 z1 = MFMA16(ah, Kh[1], Z4);
        f32x4 z2 = MFMA16(ah, Kh[2], Z4);
        f32x4 z3 = MFMA16(ah, Kh[3], Z4);
        z0 = MFMA16(al, Kh[0], z0); z0 = MFMA16(ah, Kl[0], z0);
        z1 = MFMA16(al, Kh[1], z1); z1 = MFMA16(ah, Kl[1], z1);
        z2 = MFMA16(al, Kh[2], z2); z2 = MFMA16(ah, Kl[2], z2);
        z3 = MFMA16(al, Kh[3], z3); z3 = MFMA16(ah, Kl[3], z3);
        #pragma unroll
        for (int r = 0; r < 4; ++r) {
            float hv = elem(z0[r], z1[r], z2[r], z3[r], cst[r]);
            unsigned short hh, hl;
            split2(hv, hh, hl);
            if (col < 13) {
                outH[(4 * q + r) * 24 + col]       = hh;
                outH[384 + (4 * q + r) * 24 + col] = hl;
            }
        }
    };

    auto proj = [&](int t, unsigned short* oH) {
        bf16x8 axh{}, axl{};
        if (q < 2) {
            const float* p = xrow + t * 13;
            #pragma unroll
            for (int j = 0; j < 8; ++j) {
                int k  = 8 * q + j;
                int kk = k > 12 ? 12 : k;     // clamp keeps loads in-bounds
                float v = p[kk];
                if (k > 12) v = 0.f;
                unsigned short h_, l_;
                split2(v, h_, l_);
                axh[j] = bfbits(h_); axl[j] = bfbits(l_);
            }
            if (q == 1) { axh[5] = bfbits(0x3F80); axl[5] = bfbits(0); }  // k=13 -> 1.0 (bias row)
        }
        f32x4 zp = MFMA16(axh, Kh[0], Z4);    // Kh[0]=Ph, Kh[1]=Pl (W2 aliasing)
        zp = MFMA16(axl, Kh[0], zp);
        zp = MFMA16(axh, Kh[1], zp);
        #pragma unroll
        for (int r = 0; r < 4; ++r) {
            float v = fmaxf(zp[r], 0.f);
            unsigned short hh, hl;
            split2(v, hh, hl);
            if (col < 13) {
                oH[(4 * q + r) * 24 + col]       = hh;
                oH[384 + (4 * q + r) * 24 + col] = hl;
            }
        }
    };

    float cst[4] = {0.f, 0.f, 0.f, 0.f};

    __syncthreads();                 // staging init visible
    if (role == 2) proj(0, &xh_s[grp][0][0][0]);
    __syncthreads();

    for (int i = 0; i <= 100; ++i) {
        int p = i & 1;
        if (role == 0) {
            if (i < 100)
                cell(&xh_s[grp][p][0][0], &h0_s[grp][p ^ 1][0][0],
                     &h0_s[grp][p][0][0], cst);
        } else if (role == 1) {
            if (i >= 1)
                cell(&h0_s[grp][p ^ 1][0][0], &h1_s[grp][0][0],
                     &h1_s[grp][0][0], cst);           // h1 in-place (own wave only)
        } else {
            if (i < 99) proj(i + 1, &xh_s[grp][p ^ 1][0][0]);
        }
        __syncthreads();
    }

    // ---- output projection (W1 holds final h1; bias row k=13 = b_out) ----
    if (role == 1) {
        bf16x8 Oh{}, Ol{};
        #pragma unroll
        for (int j = 0; j < 8; ++j) {
            int k = 8 * q + j;
            float w = 0.f;
            if (col < 4) {
                if (k < 13)       w = w_out[k * 4 + col];
                else if (k == 13) w = b_out[col];
            }
            unsigned short h_, l_;
            split2(w, h_, l_);
            Oh[j] = bfbits(h_); Ol[j] = bfbits(l_);
        }
        const unsigned short* pA = &h1_s[grp][0][0];
        bf16x8 ah = __builtin_bit_cast(bf16x8, *(const u16x8*)(pA + col * 24 + 8 * qh));
        bf16x8 al = __builtin_bit_cast(bf16x8, *(const u16x8*)(pA + 384 + col * 24 + 8 * qh));
        f32x4 zf = MFMA16(ah, Oh, Z4);
        zf = MFMA16(al, Oh, zf);
        zf = MFMA16(ah, Ol, zf);
        if (col < 4) {
            #pragma unroll
            for (int r = 0; r < 4; ++r)
                out[(size_t)(s0 + 4 * q + r) * 4 + col] = zf[r];
        }
    }
}

extern "C" void kernel_launch(void* const* d_in, const int* in_sizes, int n_in,
                              void* d_out, int out_size, void* d_ws, size_t ws_size,
                              hipStream_t stream) {
    (void)in_sizes; (void)n_in; (void)d_ws; (void)ws_size; (void)out_size;
    lstm_fused<<<dim3(1024), dim3(384), 0, stream>>>(
        (const float*)d_in[0], (const float*)d_in[1], (const float*)d_in[2],
        (const float*)d_in[3], (const float*)d_in[4], (const float*)d_in[5],
        (const float*)d_in[6], (const float*)d_in[7], (const float*)d_in[8],
        (float*)d_out);
}